// Round 8
// baseline (409.538 us; speedup 1.0000x reference)
//
#include <hip/hip_runtime.h>

#define B_ 2048
#define T_ 2048
#define SPW 16    // samples per block (MFMA N dimension)
#define GSTR 162  // per-g word stride in exchange buf (16 samples * 10 + 2 pad)
#define QT 512    // timesteps per x staging quarter
#define XSTR 516  // f32 stride per sample row in x LDS (pad: 2-way banks, 16B aligned)

typedef _Float16 f16x8 __attribute__((ext_vector_type(8)));
typedef float    f32x4 __attribute__((ext_vector_type(4)));
typedef unsigned u32x2 __attribute__((ext_vector_type(2)));
typedef unsigned u32x4 __attribute__((ext_vector_type(4)));

__device__ __forceinline__ unsigned pkrtz(float lo, float hi) {
    return __builtin_bit_cast(unsigned, __builtin_amdgcn_cvt_pkrtz(lo, hi));
}

// Round 8 = round 7 (343 us, proven; zero global memory in the recurrence
// loop) + three path cuts. r7 evidence: ~410 cyc/step with only ~150-180 cyc
// of issue (trans = 16 cyc/wave64 fits r4 AND r7) => ~250 cyc of pure
// barrier-to-barrier dependency stall: ds_read ~120 + chained MFMA ~60 +
// tanh ~40 + post-barrier ci + write/skew. Cuts, all scheduling-only:
//  1) parallel MFMAs (C=ci / C=0) + f32 add: -1 dependent MFMA latency.
//  2) ci affine hoisted pre-barrier (h-independent; safe now x is in LDS).
//  3) x group read double-buffered in regs: its ~120 cyc LDS latency gets
//     4-step slack instead of landing before j4=0's ci.
// Everything else (exchange layout, 1 barrier/step, tanh form, staging,
// sigma-relabeling [HW-verified r3-r7]) is identical to r7.
__global__ __launch_bounds__(256)
void rnn_mfma_4w4(
    const float* __restrict__ x, const float* __restrict__ W_ih,
    const float* __restrict__ W_hh, const float* __restrict__ b_ih,
    const float* __restrict__ b_hh, const float* __restrict__ W_fc,
    const float* __restrict__ b_fc, float* __restrict__ out)
{
    __shared__ __align__(16) float xl[SPW * XSTR];      // 33 KB x quarter
    __shared__ __align__(16) unsigned ex[2][4 * GSTR];  // [buf][g][s][10 words]
    __shared__ float fcb[4][SPW];

    const int tid = threadIdx.x;
    const int w = tid >> 6;          // wave index == tile index (rows 16w+..)
    const int l = tid & 63;
    const int s = l & 15;            // sample column (C-col / A-M-row / B-N)
    const int g = l >> 4;            // slot group; C row-quad selector
    const int sb = blockIdx.x * SPW;
    const float L2E2 = 2.8853900817779268f;  // 2*log2(e), folded into W/bias

    // ---- A-frags for tile w: slot (g,j) of chunk c holds
    // k = sigma_c(g,j) = 16*(2c+(j>>2)) + 4g + (j&3).   [HW-verified r3-r7]
    f16x8 a0, a1;
#pragma unroll
    for (int j = 0; j < 8; ++j) {
        const int k0 = 16 * (0 + (j >> 2)) + 4 * g + (j & 3);
        const int k1 = 16 * (2 + (j >> 2)) + 4 * g + (j & 3);
        a0[j] = (_Float16)(W_hh[(16 * w + s) * 64 + k0] * L2E2);
        a1[j] = (_Float16)(W_hh[(16 * w + s) * 64 + k1] * L2E2);
    }

    // ---- per-lane C-slot constants: rows 16w + 4g + r
    float wih[4], bw[4];
#pragma unroll
    for (int r = 0; r < 4; ++r) {
        const int row = 16 * w + 4 * g + r;
        wih[r] = W_ih[row] * L2E2;
        bw[r]  = (b_ih[row] + b_hh[row]) * L2E2;
    }

    // ---- exchange addresses (word granularity) ----
    const int exbase = g * GSTR + s * 10;  // this lane's sample slot
    unsigned* const wr0 = &ex[0][exbase + 2 * w];
    unsigned* const wr1 = &ex[1][exbase + 2 * w];
    const unsigned* const rd0 = &ex[0][exbase];
    const unsigned* const rd1 = &ex[1][exbase];

    // ---- state: h[r] = h_state[16w+4g+r] for sample s; h0 = 0.
    float h[4] = {0.0f, 0.0f, 0.0f, 0.0f};

    const float* xg = x + (size_t)sb * T_;  // this block's 16 sample rows
    const float* const xrow = &xl[s * XSTR];

    for (int q = 0; q < 4; ++q) {
        // ---- stage quarter q: 16 rows x 512 f32, coalesced dwordx4 ----
        __syncthreads();  // all waves done reading the previous quarter
        for (int it = tid; it < SPW * (QT / 4); it += 256) {
            const int row = it >> 7;         // 128 float4 chunks per row
            const int c4  = it & 127;
            const float4 v =
                *(const float4*)(xg + (size_t)row * T_ + q * QT + 4 * c4);
            *(float4*)&xl[row * XSTR + 4 * c4] = v;
        }
        __syncthreads();  // quarter visible (drains the staging loads once)

        float4 xq = *(const float4*)(xrow);  // group 0's x

        for (int t0 = 0; t0 < QT; t0 += 4) {
            const float4 xc = xq;
            // prefetch next group's x (lane-private LDS; 4-step slack).
            // Wraps to group 0 on the last iter; re-read after restaging.
            xq = *(const float4*)(xrow + ((t0 + 4) & (QT - 1)));
            const float xa[4] = {xc.x, xc.y, xc.z, xc.w};

#pragma unroll
            for (int j4 = 0; j4 < 4; ++j4) {
                const int buf = j4 & 1;  // t0 multiple of 4 -> buf = j4&1

                // --- publish this tile's 4 h values (f16-packed, 8B) ---
                const u32x2 pk = {pkrtz(h[0], h[1]), pkrtz(h[2], h[3])};
                *(u32x2*)(buf ? wr1 : wr0) = pk;

                // --- h-independent affine: fills the pre-barrier window ---
                f32x4 ci;
#pragma unroll
                for (int r = 0; r < 4; ++r) ci[r] = fmaf(xa[j4], wih[r], bw[r]);

                __syncthreads();  // all tiles' h_t visible (vmcnt already 0)

                // --- rebuild full B operands (lane-aligned (g,s) slot) ---
                const unsigned* rp = buf ? rd1 : rd0;
                const u32x2 e0 = *(const u32x2*)(rp + 0);  // tile 0 pair
                const u32x2 e1 = *(const u32x2*)(rp + 2);  // tile 1 pair
                const u32x2 e2 = *(const u32x2*)(rp + 4);  // tile 2 pair
                const u32x2 e3 = *(const u32x2*)(rp + 6);  // tile 3 pair
                const u32x4 q0 = {e0.x, e0.y, e1.x, e1.y};
                const u32x4 q1 = {e2.x, e2.y, e3.x, e3.y};
                const f16x8 b0 = __builtin_bit_cast(f16x8, q0);  // k =  0..31
                const f16x8 b1 = __builtin_bit_cast(f16x8, q1);  // k = 32..63

                // --- two independent MFMAs (latency-parallel) + combine ---
                const f32x4 zero = {0.0f, 0.0f, 0.0f, 0.0f};
                const f32x4 p0 =
                    __builtin_amdgcn_mfma_f32_16x16x32_f16(a0, b0, ci, 0, 0, 0);
                const f32x4 p1 =
                    __builtin_amdgcn_mfma_f32_16x16x32_f16(a1, b1, zero, 0, 0, 0);
                const f32x4 acc = p0 + p1;

                // --- tanh(pre) = 1 - 2/(exp2(2log2e*pre)+1): 8 trans ---
#pragma unroll
                for (int r = 0; r < 4; ++r) {
                    const float e = __builtin_amdgcn_exp2f(acc[r]);
                    h[r] = fmaf(-2.0f, __builtin_amdgcn_rcpf(e + 1.0f), 1.0f);
                }
            }
        }
    }

    // ---- FC head: out[s] = sum_row h[row][s] * W_fc[row] + b_fc ----
    float p = 0.0f;
#pragma unroll
    for (int r = 0; r < 4; ++r) p = fmaf(h[r], W_fc[16 * w + 4 * g + r], p);
    p += __shfl_down(p, 32);
    p += __shfl_down(p, 16);
    if (l < 16) fcb[w][l] = p;
    __syncthreads();
    if (tid < 16)
        out[sb + tid] = (fcb[0][tid] + fcb[1][tid]) + (fcb[2][tid] + fcb[3][tid]) + b_fc[0];
}

extern "C" void kernel_launch(void* const* d_in, const int* in_sizes, int n_in,
                              void* d_out, int out_size, void* d_ws, size_t ws_size,
                              hipStream_t stream) {
    const float* x    = (const float*)d_in[0];
    const float* W_ih = (const float*)d_in[1];
    const float* W_hh = (const float*)d_in[2];
    const float* b_ih = (const float*)d_in[3];
    const float* b_hh = (const float*)d_in[4];
    const float* W_fc = (const float*)d_in[5];
    const float* b_fc = (const float*)d_in[6];
    float* out = (float*)d_out;

    rnn_mfma_4w4<<<dim3(B_ / SPW), dim3(256), 0, stream>>>(x, W_ih, W_hh, b_ih, b_hh,
                                                           W_fc, b_fc, out);
}